// Round 9
// baseline (145.491 us; speedup 1.0000x reference)
//
#include <hip/hip_runtime.h>

// Tricubic B-spline eval via fixed-capacity spatial buckets.
// p=3, NC=64/axis, 61 spans/axis, DOUT=3, knots t[i]=clamp((i-3)/61,0,1).
// Cells: 8 spans/axis -> 512 cells, bucket cap 2560, overflow list for
// correctness. Window 11^3 float4 = 21.3 KB LDS.
// R5-R12 lessons: 256-thr packing; NO 2nd launch_bounds arg (caps VGPR at
//   ~256/N -> spills); gcursor padded 1 counter/128B line; eval XCD swizzle
//   (FETCH 21->12MB); eval ~46us vs ~27us LDS floor.
// R13: cooperative fusion CRASHED the harness -- hipLaunchCooperativeKernel
//   during graph capture invalidates the capture (fallback also dies).
//   Never use cooperative launch in this harness.
// R14: measurement round. Eval split into TWO dispatches over half the
//   points each (same 1536-block grid -> 6 blocks/CU residency preserved;
//   window/sort overhead duplicated, B is L2-hot). Each half ~25-29us <
//   scatter if S>29 -> scatter_staged enters top-5 for the FIRST direct
//   measurement. Scatter/memset byte-identical to R12.

#define NC 64
#define NSEG 61
#define NCELLS 512
#define GSTRIDE 32      // ints per gcursor slot: 1 counter per 128B line
#define WDIM 11
#define CAP 2560
#define NPART 3
#define PARTMAX 896     // max points per third-cell
#define EVAL_BLOCKS (NPART * NCELLS)
#define CHUNK_S 2048    // scatter queries per block
#define OVF_CAP 4096

typedef float vfloat4 __attribute__((ext_vector_type(4)));

__device__ __forceinline__ float rcpf(float x) {
#if __has_builtin(__builtin_amdgcn_rcpf)
  return __builtin_amdgcn_rcpf(x);
#else
  return 1.0f / x;
#endif
}

__device__ __forceinline__ int span_of(float x) {
  float xc = fminf(fmaxf(x, 0.0f), 1.0f);
  int j = (int)floorf(xc * (float)NSEG);
  return j > NSEG - 1 ? NSEG - 1 : (j < 0 ? 0 : j);
}

__device__ __forceinline__ float knotv(int i) {
  float v = (float)(i - 3) * (1.0f / (float)NSEG);
  return fminf(fmaxf(v, 0.0f), 1.0f);
}

// Cox-de Boor (A2.2): span j (k=j+3), 4 nonzero basis values for idx j..j+3.
__device__ __forceinline__ void basis4(float x, int j, float N[4]) {
  float xc = fminf(fmaxf(x, 0.0f), 1.0f);
  int k = j + 3;
  float left[4], right[4];
  N[0] = 1.0f;
#pragma unroll
  for (int jj = 1; jj <= 3; ++jj) {
    left[jj] = xc - knotv(k + 1 - jj);
    right[jj] = knotv(k + jj) - xc;
    float saved = 0.0f;
#pragma unroll
    for (int r = 0; r < jj; ++r) {
      float temp = N[r] * rcpf(right[r + 1] + left[jj - r]);
      N[r] = saved + right[r + 1] * temp;
      saved = left[jj - r] * temp;
    }
    N[jj] = saved;
  }
}

__device__ __forceinline__ void eval_point(float x, float y, float z, int jx,
                                           int jy, int jz,
                                           const float* __restrict__ cp,
                                           float o[3]) {
  float Nx[4], Ny[4], Nz[4];
  basis4(x, jx, Nx);
  basis4(y, jy, Ny);
  basis4(z, jz, Nz);
  float ax = 0, ay = 0, az = 0;
#pragma unroll 1
  for (int c = 0; c < 4; ++c) {
#pragma unroll
    for (int b = 0; b < 4; ++b) {
      float w = Ny[b] * Nz[c];
      const float* row = cp + 3 * (size_t)(jx + NC * (jy + b + NC * (jz + c)));
      vfloat4 f0, f1, f2;
      __builtin_memcpy(&f0, row + 0, 16);
      __builtin_memcpy(&f1, row + 4, 16);
      __builtin_memcpy(&f2, row + 8, 16);
      ax += w * (Nx[0] * f0.x + Nx[1] * f0.w + Nx[2] * f1.z + Nx[3] * f2.y);
      ay += w * (Nx[0] * f0.y + Nx[1] * f1.x + Nx[2] * f1.w + Nx[3] * f2.z);
      az += w * (Nx[0] * f0.z + Nx[1] * f1.y + Nx[2] * f2.x + Nx[3] * f2.w);
    }
  }
  o[0] = ax; o[1] = ay; o[2] = az;
}

// Exclusive prefix scan of arr[512] in LDS with 256 threads (2 elems/thread),
// shfl-based, 3 barriers. aux >= 4 ints. ALL 256 threads must call.
__device__ __forceinline__ void scan512_excl256(int* arr, int* aux) {
  int tid = threadIdx.x;
  int lane = tid & 63, wv = tid >> 6;  // 4 waves
  int a0 = arr[2 * tid], a1 = arr[2 * tid + 1];
  int s = a0 + a1;
  int inc = s;
#pragma unroll
  for (int off = 1; off < 64; off <<= 1) {
    int t = __shfl_up(inc, off, 64);
    if (lane >= off) inc += t;
  }
  if (lane == 63) aux[wv] = inc;
  __syncthreads();
  if (tid < 64) {
    int a = (tid < 4) ? aux[tid] : 0;
    int ainc = a;
#pragma unroll
    for (int off = 1; off < 4; off <<= 1) {
      int t = __shfl_up(ainc, off, 64);
      if (lane >= off) ainc += t;
    }
    if (tid < 4) aux[tid] = ainc - a;  // exclusive wave offsets
  }
  __syncthreads();
  int excl = (inc - s) + aux[wv];
  arr[2 * tid] = excl;
  arr[2 * tid + 1] = excl + a0;
  __syncthreads();
}

// ---------------- scatter: LDS-staged, cell-ordered coalesced writes --------
// Byte-identical to R12 (clean measurement target).

__global__ __launch_bounds__(256) void scatter_staged(
    const float* __restrict__ q, int* __restrict__ gcursor,
    int* __restrict__ ovfcnt, float4* __restrict__ ovf,
    float4* __restrict__ sorted, int nq) {
  __shared__ int hist[NCELLS];   // counts -> (after scan) local excl base
  __shared__ int gb[NCELLS];     // global segment base per cell
  __shared__ int lcur[NCELLS];   // local rank cursors
  __shared__ int aux[4];
  __shared__ float4 stage[CHUNK_S];  // 32 KB
  __shared__ int addr[CHUNK_S];      // 8 KB
  int tid = threadIdx.x;
  int s = blockIdx.x * CHUNK_S, e = min(nq, s + CHUNK_S);
  int nblk = e - s;
  hist[tid] = 0; hist[tid + 256] = 0;
  lcur[tid] = 0; lcur[tid + 256] = 0;
  __syncthreads();

  float xs[8], ys[8], zs[8];
  int cells[8];
  unsigned us[8];
#pragma unroll
  for (int it = 0; it < 8; ++it) {
    int i = s + it * 256 + tid;
    cells[it] = -1;
    if (i < e) {
      float xyz[3];
      __builtin_memcpy(xyz, q + 3 * (size_t)i, 12);
      xs[it] = xyz[0]; ys[it] = xyz[1]; zs[it] = xyz[2];
      int jx = span_of(xyz[0]), jy = span_of(xyz[1]), jz = span_of(xyz[2]);
      cells[it] = (jx >> 3) + 8 * (jy >> 3) + 64 * (jz >> 3);
      us[it] = (unsigned)i | ((unsigned)(jx & 7) << 20) |
               ((unsigned)(jy & 7) << 23) | ((unsigned)(jz & 7) << 26);
      atomicAdd(&hist[cells[it]], 1);
    }
  }
  __syncthreads();
  // claim global segment per nonempty cell; padded counters: 1 per 128B line
  int n0 = hist[tid], n1 = hist[tid + 256];
  gb[tid] = n0 ? atomicAdd(&gcursor[tid * GSTRIDE], n0) : 0;
  gb[tid + 256] = n1 ? atomicAdd(&gcursor[(tid + 256) * GSTRIDE], n1) : 0;
  scan512_excl256(hist, aux);  // hist[c] = local excl base (internal barriers)
  // stage in cell-sorted order
#pragma unroll
  for (int it = 0; it < 8; ++it) {
    int cell = cells[it];
    if (cell < 0) continue;
    int rank = atomicAdd(&lcur[cell], 1);
    int rloc = hist[cell] + rank;
    int rg = gb[cell] + rank;
    if (rg < CAP) {
      stage[rloc] = make_float4(xs[it], ys[it], zs[it],
                                __int_as_float((int)us[it]));
      addr[rloc] = cell * CAP + rg;
    } else {
      addr[rloc] = -1;
      int p = atomicAdd(ovfcnt, 1);
      if (p < OVF_CAP)
        ovf[p] = make_float4(xs[it], ys[it], zs[it],
                             __int_as_float((int)(us[it] & 0xFFFFFu)));
    }
  }
  __syncthreads();
  // drain: consecutive lanes -> consecutive addresses within cell segments
  for (int j = tid; j < nblk; j += 256) {
    int a = addr[j];
    if (a >= 0) sorted[a] = stage[j];
  }
}

// ---------------- eval: third-cell blocks, point-range split ----------------
// 256 thr = 1 wave/SIMD; 1536 blocks, LDS 25.6KB -> 6 blocks/CU per dispatch.
// XCD swizzle keeps a cell's 3 parts on one XCD's L2.
// half=0: first floor(n/2) points of each part; half=1: remainder + ovf tail.

__global__ __launch_bounds__(256) void eval_kernel(
    const float4* __restrict__ sorted, const int* __restrict__ cellcnt,
    const float* __restrict__ cp, float* __restrict__ out,
    const int* __restrict__ ovfcnt, const float4* __restrict__ ovf,
    int half) {
  __shared__ float4 lds[WDIM * WDIM * WDIM];  // 21296 B
  __shared__ int bins[NCELLS];                // 2048 B
  __shared__ unsigned short order[PARTMAX];   // 1792 B
  __shared__ int aux[4];
  int tid = threadIdx.x;
  int lb = (int)((blockIdx.x & 7) * (EVAL_BLOCKS / 8) + (blockIdx.x >> 3));
  int cid = lb / NPART, part = lb % NPART;
  int cnt = min(cellcnt[cid * GSTRIDE], CAP);
  int h = cnt / NPART;
  int q0 = part * h;
  int nTot = (part == NPART - 1) ? (cnt - 2 * h) : h;
  int nHalf = nTot >> 1;
  int off = half ? nHalf : 0;
  int n = half ? (nTot - nHalf) : nHalf;

  if (n > 0) {  // block-uniform; barriers inside are safe
    size_t base = (size_t)cid * CAP + q0 + off;
    int ox = (cid & 7) * 8, oy = ((cid >> 3) & 7) * 8, oz = (cid >> 6) * 8;

    // stage 11^3 control-point window (L2/L3-resident source)
    for (int e2 = tid; e2 < WDIM * WDIM * WDIM; e2 += 256) {
      int lx = e2 % WDIM, t = e2 / WDIM;
      int ly = t % WDIM, lz = t / WDIM;
      int gx = min(ox + lx, NC - 1), gy = min(oy + ly, NC - 1),
          gz = min(oz + lz, NC - 1);
      const float* p = cp + 3 * (size_t)(gx + NC * (gy + NC * gz));
      lds[e2] = make_float4(p[0], p[1], p[2], 0.0f);
    }
    bins[tid] = 0;
    bins[tid + 256] = 0;
    // key probe: only the .w word (subspan key = lx + 8*ly + 64*lz)
    int k[4], r[4];
#pragma unroll
    for (int pr = 0; pr < 4; ++pr) {
      k[pr] = -1;
      r[pr] = 0;
      if (tid + pr * 256 < n)
        k[pr] = (int)(((unsigned)__float_as_int(
                          ((const float*)(sorted + base + tid + pr * 256))[3])
                       >> 20) & 511u);
    }
    __syncthreads();
#pragma unroll
    for (int pr = 0; pr < 4; ++pr)
      if (k[pr] >= 0) r[pr] = atomicAdd(&bins[k[pr]], 1);
    __syncthreads();
    scan512_excl256(bins, aux);
#pragma unroll
    for (int pr = 0; pr < 4; ++pr)
      if (k[pr] >= 0)
        order[bins[k[pr]] + r[pr]] = (unsigned short)(tid + pr * 256);
    __syncthreads();

    for (int t2 = tid; t2 < n; t2 += 256) {
      int lidx = order[t2];
      float4 sp = sorted[base + lidx];  // L1/L2-resident (just probed)
      unsigned u = (unsigned)__float_as_int(sp.w);
      int oi = (int)(u & 0xFFFFFu);
      int lx0 = (int)((u >> 20) & 7), ly0 = (int)((u >> 23) & 7),
          lz0 = (int)((u >> 26) & 7);
      float Nx[4], Ny[4], Nz[4];
      basis4(sp.x, ox + lx0, Nx);
      basis4(sp.y, oy + ly0, Ny);
      basis4(sp.z, oz + lz0, Nz);

      float ax = 0.0f, ay = 0.0f, az = 0.0f;
#pragma unroll
      for (int c = 0; c < 4; ++c) {
#pragma unroll
        for (int b = 0; b < 4; ++b) {
          float w = Ny[b] * Nz[c];
          const float4* row = &lds[((lz0 + c) * WDIM + (ly0 + b)) * WDIM + lx0];
          float4 p0 = row[0], p1 = row[1], p2 = row[2], p3 = row[3];
          ax += w * (Nx[0] * p0.x + Nx[1] * p1.x + Nx[2] * p2.x + Nx[3] * p3.x);
          ay += w * (Nx[0] * p0.y + Nx[1] * p1.y + Nx[2] * p2.y + Nx[3] * p3.y);
          az += w * (Nx[0] * p0.z + Nx[1] * p1.z + Nx[2] * p2.z + Nx[3] * p3.z);
        }
      }
      float o[3] = {ax, ay, az};
      __builtin_memcpy(out + 3 * (size_t)oi, o, 12);
    }
  }

  // fused overflow tail: dispatch half=1 only (ovf list complete pre-launch)
  if (half) {
    int novf = min(*ovfcnt, OVF_CAP);
    for (int i = blockIdx.x * 256 + tid; i < novf; i += EVAL_BLOCKS * 256) {
      float4 sp = ovf[i];
      int oi = __float_as_int(sp.w);
      float o[3];
      eval_point(sp.x, sp.y, sp.z, span_of(sp.x), span_of(sp.y),
                 span_of(sp.z), cp, o);
      __builtin_memcpy(out + 3 * (size_t)oi, o, 12);
    }
  }
}

// ---------------- fallback: direct ----------------
__global__ __launch_bounds__(256) void spline_direct_kernel(
    const float* __restrict__ q, const float* __restrict__ cp,
    float* __restrict__ out, int nq) {
  int i = blockIdx.x * 256 + threadIdx.x;
  if (i >= nq) return;
  float xyz[3];
  __builtin_memcpy(xyz, q + 3 * (size_t)i, 12);
  float o[3];
  eval_point(xyz[0], xyz[1], xyz[2], span_of(xyz[0]), span_of(xyz[1]),
             span_of(xyz[2]), cp, o);
  __builtin_memcpy(out + 3 * (size_t)i, o, 12);
}

extern "C" void kernel_launch(void* const* d_in, const int* in_sizes, int n_in,
                              void* d_out, int out_size, void* d_ws,
                              size_t ws_size, hipStream_t stream) {
  const float* queries = (const float*)d_in[0];
  const float* control = (const float*)d_in[1];
  float* out = (float*)d_out;
  int nq = in_sizes[0] / 3;

  // ws: gcursor[512*GSTRIDE] | ovfcnt | pad16 | ovf[OVF_CAP] f4 | sorted f4
  size_t meta = ((size_t)NCELLS * GSTRIDE + 1) * sizeof(int);
  size_t metap = (meta + 15) & ~15ull;
  size_t need = metap + (size_t)OVF_CAP * 16 + (size_t)NCELLS * CAP * 16;

  if (nq <= (1 << 20) && ws_size >= need) {
    int* gcursor = (int*)d_ws;
    int* ovfcnt = gcursor + (size_t)NCELLS * GSTRIDE;
    float4* ovf = (float4*)((char*)d_ws + metap);
    float4* sorted = ovf + OVF_CAP;
    hipMemsetAsync(d_ws, 0, meta, stream);
    int nb = (nq + CHUNK_S - 1) / CHUNK_S;
    scatter_staged<<<nb, 256, 0, stream>>>(queries, gcursor, ovfcnt, ovf,
                                           sorted, nq);
    eval_kernel<<<EVAL_BLOCKS, 256, 0, stream>>>(sorted, gcursor, control, out,
                                                 ovfcnt, ovf, 0);
    eval_kernel<<<EVAL_BLOCKS, 256, 0, stream>>>(sorted, gcursor, control, out,
                                                 ovfcnt, ovf, 1);
  } else {
    spline_direct_kernel<<<(nq + 255) / 256, 256, 0, stream>>>(queries, control,
                                                               out, nq);
  }
}

// Round 11
// 138.810 us; speedup vs baseline: 1.0481x; 1.0481x over previous
//
#include <hip/hip_runtime.h>

// Tricubic B-spline eval via fixed-capacity spatial buckets.
// p=3, NC=64/axis, 61 spans/axis, DOUT=3, knots t[i]=clamp((i-3)/61,0,1).
// Cells: 8 spans/axis -> 512 cells, bucket cap 2560, overflow list for
// correctness. Window 11^3 float4 = 21.3 KB LDS.
// Lessons: 256-thr packing; NO 2nd launch_bounds arg (caps VGPR ~256/N ->
//   spills); gcursor padded 1 counter/128B line; eval XCD swizzle; no
//   cooperative launch (graph capture dies, R13).
// R14 (split-eval measurement): top-5 = __amd_rocclr_fillBufferAligned,
//   268MB @ 78% HBM peak = ~43us PER ITERATION: the harness's 256MiB ws
//   re-poison. UNCONTROLLABLE floor. True kernel budget ~84us: eval 46
//   (= ~30 compute + ~16 window/sort/dispatch overhead, measured via the
//   split's +16us), scatter ~28-38 (<42.4, never top-5), gaps ~8.
// R15: revert split (single eval). Scatter A/B: CHUNK_S 2048->1024 with
//   padding HELD FIXED (R11 tested 1024-unpadded, R12 2048-padded --
//   confounded). LDS 46->26.6KB -> 6 blocks/CU, 977 blocks vs 489@<2/CU.
//   Decides occupancy-vs-chunk-granularity for scatter definitively.
// R16: R15 never ran (container acquisition failed twice — infra, not
//   kernel). Identical resubmission to preserve the clean A/B.

#define NC 64
#define NSEG 61
#define NCELLS 512
#define GSTRIDE 32      // ints per gcursor slot: 1 counter per 128B line
#define WDIM 11
#define CAP 2560
#define NPART 3
#define PARTMAX 896     // max points per third-cell
#define EVAL_BLOCKS (NPART * NCELLS)
#define CHUNK_S 1024    // scatter queries per block (A/B variable)
#define OVF_CAP 4096

typedef float vfloat4 __attribute__((ext_vector_type(4)));

__device__ __forceinline__ float rcpf(float x) {
#if __has_builtin(__builtin_amdgcn_rcpf)
  return __builtin_amdgcn_rcpf(x);
#else
  return 1.0f / x;
#endif
}

__device__ __forceinline__ int span_of(float x) {
  float xc = fminf(fmaxf(x, 0.0f), 1.0f);
  int j = (int)floorf(xc * (float)NSEG);
  return j > NSEG - 1 ? NSEG - 1 : (j < 0 ? 0 : j);
}

__device__ __forceinline__ float knotv(int i) {
  float v = (float)(i - 3) * (1.0f / (float)NSEG);
  return fminf(fmaxf(v, 0.0f), 1.0f);
}

// Cox-de Boor (A2.2): span j (k=j+3), 4 nonzero basis values for idx j..j+3.
__device__ __forceinline__ void basis4(float x, int j, float N[4]) {
  float xc = fminf(fmaxf(x, 0.0f), 1.0f);
  int k = j + 3;
  float left[4], right[4];
  N[0] = 1.0f;
#pragma unroll
  for (int jj = 1; jj <= 3; ++jj) {
    left[jj] = xc - knotv(k + 1 - jj);
    right[jj] = knotv(k + jj) - xc;
    float saved = 0.0f;
#pragma unroll
    for (int r = 0; r < jj; ++r) {
      float temp = N[r] * rcpf(right[r + 1] + left[jj - r]);
      N[r] = saved + right[r + 1] * temp;
      saved = left[jj - r] * temp;
    }
    N[jj] = saved;
  }
}

__device__ __forceinline__ void eval_point(float x, float y, float z, int jx,
                                           int jy, int jz,
                                           const float* __restrict__ cp,
                                           float o[3]) {
  float Nx[4], Ny[4], Nz[4];
  basis4(x, jx, Nx);
  basis4(y, jy, Ny);
  basis4(z, jz, Nz);
  float ax = 0, ay = 0, az = 0;
#pragma unroll 1
  for (int c = 0; c < 4; ++c) {
#pragma unroll
    for (int b = 0; b < 4; ++b) {
      float w = Ny[b] * Nz[c];
      const float* row = cp + 3 * (size_t)(jx + NC * (jy + b + NC * (jz + c)));
      vfloat4 f0, f1, f2;
      __builtin_memcpy(&f0, row + 0, 16);
      __builtin_memcpy(&f1, row + 4, 16);
      __builtin_memcpy(&f2, row + 8, 16);
      ax += w * (Nx[0] * f0.x + Nx[1] * f0.w + Nx[2] * f1.z + Nx[3] * f2.y);
      ay += w * (Nx[0] * f0.y + Nx[1] * f1.x + Nx[2] * f1.w + Nx[3] * f2.z);
      az += w * (Nx[0] * f0.z + Nx[1] * f1.y + Nx[2] * f2.x + Nx[3] * f2.w);
    }
  }
  o[0] = ax; o[1] = ay; o[2] = az;
}

// Exclusive prefix scan of arr[512] in LDS with 256 threads (2 elems/thread),
// shfl-based, 3 barriers. aux >= 4 ints. ALL 256 threads must call.
__device__ __forceinline__ void scan512_excl256(int* arr, int* aux) {
  int tid = threadIdx.x;
  int lane = tid & 63, wv = tid >> 6;  // 4 waves
  int a0 = arr[2 * tid], a1 = arr[2 * tid + 1];
  int s = a0 + a1;
  int inc = s;
#pragma unroll
  for (int off = 1; off < 64; off <<= 1) {
    int t = __shfl_up(inc, off, 64);
    if (lane >= off) inc += t;
  }
  if (lane == 63) aux[wv] = inc;
  __syncthreads();
  if (tid < 64) {
    int a = (tid < 4) ? aux[tid] : 0;
    int ainc = a;
#pragma unroll
    for (int off = 1; off < 4; off <<= 1) {
      int t = __shfl_up(ainc, off, 64);
      if (lane >= off) ainc += t;
    }
    if (tid < 4) aux[tid] = ainc - a;  // exclusive wave offsets
  }
  __syncthreads();
  int excl = (inc - s) + aux[wv];
  arr[2 * tid] = excl;
  arr[2 * tid + 1] = excl + a0;
  __syncthreads();
}

// ---------------- scatter: LDS-staged, cell-ordered coalesced writes --------
// CHUNK_S=1024, LDS ~26.6KB -> 6 blocks/CU (vs R12: 2048, 46KB, <2/CU).
// Padded gcursor held fixed from R12 for a clean A/B on chunk size.

__global__ __launch_bounds__(256) void scatter_staged(
    const float* __restrict__ q, int* __restrict__ gcursor,
    int* __restrict__ ovfcnt, float4* __restrict__ ovf,
    float4* __restrict__ sorted, int nq) {
  __shared__ int hist[NCELLS];   // counts -> (after scan) local excl base
  __shared__ int gb[NCELLS];     // global segment base per cell
  __shared__ int lcur[NCELLS];   // local rank cursors
  __shared__ int aux[4];
  __shared__ float4 stage[CHUNK_S];  // 16 KB
  __shared__ int addr[CHUNK_S];      // 4 KB
  int tid = threadIdx.x;
  int s = blockIdx.x * CHUNK_S, e = min(nq, s + CHUNK_S);
  int nblk = e - s;
  hist[tid] = 0; hist[tid + 256] = 0;
  lcur[tid] = 0; lcur[tid + 256] = 0;
  __syncthreads();

  float xs[4], ys[4], zs[4];
  int cells[4];
  unsigned us[4];
#pragma unroll
  for (int it = 0; it < 4; ++it) {
    int i = s + it * 256 + tid;
    cells[it] = -1;
    if (i < e) {
      float xyz[3];
      __builtin_memcpy(xyz, q + 3 * (size_t)i, 12);
      xs[it] = xyz[0]; ys[it] = xyz[1]; zs[it] = xyz[2];
      int jx = span_of(xyz[0]), jy = span_of(xyz[1]), jz = span_of(xyz[2]);
      cells[it] = (jx >> 3) + 8 * (jy >> 3) + 64 * (jz >> 3);
      us[it] = (unsigned)i | ((unsigned)(jx & 7) << 20) |
               ((unsigned)(jy & 7) << 23) | ((unsigned)(jz & 7) << 26);
      atomicAdd(&hist[cells[it]], 1);
    }
  }
  __syncthreads();
  // claim global segment per nonempty cell; padded counters: 1 per 128B line
  int n0 = hist[tid], n1 = hist[tid + 256];
  gb[tid] = n0 ? atomicAdd(&gcursor[tid * GSTRIDE], n0) : 0;
  gb[tid + 256] = n1 ? atomicAdd(&gcursor[(tid + 256) * GSTRIDE], n1) : 0;
  scan512_excl256(hist, aux);  // hist[c] = local excl base (internal barriers)
  // stage in cell-sorted order
#pragma unroll
  for (int it = 0; it < 4; ++it) {
    int cell = cells[it];
    if (cell < 0) continue;
    int rank = atomicAdd(&lcur[cell], 1);
    int rloc = hist[cell] + rank;
    int rg = gb[cell] + rank;
    if (rg < CAP) {
      stage[rloc] = make_float4(xs[it], ys[it], zs[it],
                                __int_as_float((int)us[it]));
      addr[rloc] = cell * CAP + rg;
    } else {
      addr[rloc] = -1;
      int p = atomicAdd(ovfcnt, 1);
      if (p < OVF_CAP)
        ovf[p] = make_float4(xs[it], ys[it], zs[it],
                             __int_as_float((int)(us[it] & 0xFFFFFu)));
    }
  }
  __syncthreads();
  // drain: consecutive lanes -> consecutive addresses within cell segments
  for (int j = tid; j < nblk; j += 256) {
    int a = addr[j];
    if (a >= 0) sorted[a] = stage[j];
  }
}

// ---------------- eval: third-cell blocks, LDS window + subspan sort --------
// 256 thr = 1 wave/SIMD; 1536 blocks, LDS 25.6KB -> 6 blocks/CU, all
// resident. XCD swizzle keeps a cell's 3 parts on one XCD's L2. (R12 body.)

__global__ __launch_bounds__(256) void eval_kernel(
    const float4* __restrict__ sorted, const int* __restrict__ cellcnt,
    const float* __restrict__ cp, float* __restrict__ out,
    const int* __restrict__ ovfcnt, const float4* __restrict__ ovf) {
  __shared__ float4 lds[WDIM * WDIM * WDIM];  // 21296 B
  __shared__ int bins[NCELLS];                // 2048 B
  __shared__ unsigned short order[PARTMAX];   // 1792 B
  __shared__ int aux[4];
  int tid = threadIdx.x;
  int lb = (int)((blockIdx.x & 7) * (EVAL_BLOCKS / 8) + (blockIdx.x >> 3));
  int cid = lb / NPART, part = lb % NPART;
  int cnt = min(cellcnt[cid * GSTRIDE], CAP);
  int h = cnt / NPART;
  int q0 = part * h;
  int n = (part == NPART - 1) ? (cnt - 2 * h) : h;

  if (n > 0) {  // block-uniform; barriers inside are safe
    size_t base = (size_t)cid * CAP + q0;
    int ox = (cid & 7) * 8, oy = ((cid >> 3) & 7) * 8, oz = (cid >> 6) * 8;

    // stage 11^3 control-point window (L2/L3-resident source)
    for (int e2 = tid; e2 < WDIM * WDIM * WDIM; e2 += 256) {
      int lx = e2 % WDIM, t = e2 / WDIM;
      int ly = t % WDIM, lz = t / WDIM;
      int gx = min(ox + lx, NC - 1), gy = min(oy + ly, NC - 1),
          gz = min(oz + lz, NC - 1);
      const float* p = cp + 3 * (size_t)(gx + NC * (gy + NC * gz));
      lds[e2] = make_float4(p[0], p[1], p[2], 0.0f);
    }
    bins[tid] = 0;
    bins[tid + 256] = 0;
    // key probe: only the .w word (subspan key = lx + 8*ly + 64*lz)
    int k[4], r[4];
#pragma unroll
    for (int pr = 0; pr < 4; ++pr) {
      k[pr] = -1;
      r[pr] = 0;
      if (tid + pr * 256 < n)
        k[pr] = (int)(((unsigned)__float_as_int(
                          ((const float*)(sorted + base + tid + pr * 256))[3])
                       >> 20) & 511u);
    }
    __syncthreads();
#pragma unroll
    for (int pr = 0; pr < 4; ++pr)
      if (k[pr] >= 0) r[pr] = atomicAdd(&bins[k[pr]], 1);
    __syncthreads();
    scan512_excl256(bins, aux);
#pragma unroll
    for (int pr = 0; pr < 4; ++pr)
      if (k[pr] >= 0)
        order[bins[k[pr]] + r[pr]] = (unsigned short)(tid + pr * 256);
    __syncthreads();

    for (int t2 = tid; t2 < n; t2 += 256) {
      int lidx = order[t2];
      float4 sp = sorted[base + lidx];  // L1/L2-resident (just probed)
      unsigned u = (unsigned)__float_as_int(sp.w);
      int oi = (int)(u & 0xFFFFFu);
      int lx0 = (int)((u >> 20) & 7), ly0 = (int)((u >> 23) & 7),
          lz0 = (int)((u >> 26) & 7);
      float Nx[4], Ny[4], Nz[4];
      basis4(sp.x, ox + lx0, Nx);
      basis4(sp.y, oy + ly0, Ny);
      basis4(sp.z, oz + lz0, Nz);

      float ax = 0.0f, ay = 0.0f, az = 0.0f;
#pragma unroll
      for (int c = 0; c < 4; ++c) {
#pragma unroll
        for (int b = 0; b < 4; ++b) {
          float w = Ny[b] * Nz[c];
          const float4* row = &lds[((lz0 + c) * WDIM + (ly0 + b)) * WDIM + lx0];
          float4 p0 = row[0], p1 = row[1], p2 = row[2], p3 = row[3];
          ax += w * (Nx[0] * p0.x + Nx[1] * p1.x + Nx[2] * p2.x + Nx[3] * p3.x);
          ay += w * (Nx[0] * p0.y + Nx[1] * p1.y + Nx[2] * p2.y + Nx[3] * p3.y);
          az += w * (Nx[0] * p0.z + Nx[1] * p1.z + Nx[2] * p2.z + Nx[3] * p3.z);
        }
      }
      float o[3] = {ax, ay, az};
      __builtin_memcpy(out + 3 * (size_t)oi, o, 12);
    }
  }

  // fused overflow tail (ovf list complete: scatter finished before launch)
  int novf = min(*ovfcnt, OVF_CAP);
  for (int i = blockIdx.x * 256 + tid; i < novf; i += EVAL_BLOCKS * 256) {
    float4 sp = ovf[i];
    int oi = __float_as_int(sp.w);
    float o[3];
    eval_point(sp.x, sp.y, sp.z, span_of(sp.x), span_of(sp.y), span_of(sp.z),
               cp, o);
    __builtin_memcpy(out + 3 * (size_t)oi, o, 12);
  }
}

// ---------------- fallback: direct ----------------
__global__ __launch_bounds__(256) void spline_direct_kernel(
    const float* __restrict__ q, const float* __restrict__ cp,
    float* __restrict__ out, int nq) {
  int i = blockIdx.x * 256 + threadIdx.x;
  if (i >= nq) return;
  float xyz[3];
  __builtin_memcpy(xyz, q + 3 * (size_t)i, 12);
  float o[3];
  eval_point(xyz[0], xyz[1], xyz[2], span_of(xyz[0]), span_of(xyz[1]),
             span_of(xyz[2]), cp, o);
  __builtin_memcpy(out + 3 * (size_t)i, o, 12);
}

extern "C" void kernel_launch(void* const* d_in, const int* in_sizes, int n_in,
                              void* d_out, int out_size, void* d_ws,
                              size_t ws_size, hipStream_t stream) {
  const float* queries = (const float*)d_in[0];
  const float* control = (const float*)d_in[1];
  float* out = (float*)d_out;
  int nq = in_sizes[0] / 3;

  // ws: gcursor[512*GSTRIDE] | ovfcnt | pad16 | ovf[OVF_CAP] f4 | sorted f4
  size_t meta = ((size_t)NCELLS * GSTRIDE + 1) * sizeof(int);
  size_t metap = (meta + 15) & ~15ull;
  size_t need = metap + (size_t)OVF_CAP * 16 + (size_t)NCELLS * CAP * 16;

  if (nq <= (1 << 20) && ws_size >= need) {
    int* gcursor = (int*)d_ws;
    int* ovfcnt = gcursor + (size_t)NCELLS * GSTRIDE;
    float4* ovf = (float4*)((char*)d_ws + metap);
    float4* sorted = ovf + OVF_CAP;
    hipMemsetAsync(d_ws, 0, meta, stream);
    int nb = (nq + CHUNK_S - 1) / CHUNK_S;
    scatter_staged<<<nb, 256, 0, stream>>>(queries, gcursor, ovfcnt, ovf,
                                           sorted, nq);
    eval_kernel<<<EVAL_BLOCKS, 256, 0, stream>>>(sorted, gcursor, control, out,
                                                 ovfcnt, ovf);
  } else {
    spline_direct_kernel<<<(nq + 255) / 256, 256, 0, stream>>>(queries, control,
                                                               out, nq);
  }
}

// Round 12
// 129.880 us; speedup vs baseline: 1.1202x; 1.0688x over previous
//
#include <hip/hip_runtime.h>

// Tricubic B-spline eval via fixed-capacity spatial buckets.
// p=3, NC=64/axis, 61 spans/axis, DOUT=3, knots t[i]=clamp((i-3)/61,0,1).
// Cells: 8 spans/axis -> 512 cells, bucket cap 2560, overflow list for
// correctness. Window 11^3 float4 = 21.3 KB LDS.
// Lessons: 256-thr packing; NO 2nd launch_bounds arg (caps VGPR ~256/N ->
//   spills, R9/R10); gcursor padded 1 counter/128B line (-7us); eval XCD
//   swizzle (FETCH 21->12MB); no cooperative launch (graph capture, R13);
//   harness fill = 43us/iter floor (R14).
// R16 A/B verdict: scatter CHUNK_S 2048 > 1024 with padding fixed (129.1 vs
//   138.8). Scatter is per-block serial machinery x block count; occupancy
//   does NOT amortize it. 489-block 2048-chunk shape is final.
// Eval gap (46 vs ~27us LDS floor) = phase-correlated stage/sort overhead
//   (all blocks in lockstep phases); structural fixes all fail arithmetic
//   (512thr hits VGPR-72 wave quantization; LDS box forces 6 blocks/CU).
// R17: restore R12 config + vectorize window stage (3 scalar loads -> one
//   16B load per element; .w garbage unused; guarded at buffer end).

#define NC 64
#define NSEG 61
#define NCELLS 512
#define GSTRIDE 32      // ints per gcursor slot: 1 counter per 128B line
#define WDIM 11
#define CAP 2560
#define NPART 3
#define PARTMAX 896     // max points per third-cell
#define EVAL_BLOCKS (NPART * NCELLS)
#define CHUNK_S 2048    // scatter queries per block (R16: 2048 beats 1024)
#define OVF_CAP 4096

typedef float vfloat4 __attribute__((ext_vector_type(4)));

__device__ __forceinline__ float rcpf(float x) {
#if __has_builtin(__builtin_amdgcn_rcpf)
  return __builtin_amdgcn_rcpf(x);
#else
  return 1.0f / x;
#endif
}

__device__ __forceinline__ int span_of(float x) {
  float xc = fminf(fmaxf(x, 0.0f), 1.0f);
  int j = (int)floorf(xc * (float)NSEG);
  return j > NSEG - 1 ? NSEG - 1 : (j < 0 ? 0 : j);
}

__device__ __forceinline__ float knotv(int i) {
  float v = (float)(i - 3) * (1.0f / (float)NSEG);
  return fminf(fmaxf(v, 0.0f), 1.0f);
}

// Cox-de Boor (A2.2): span j (k=j+3), 4 nonzero basis values for idx j..j+3.
__device__ __forceinline__ void basis4(float x, int j, float N[4]) {
  float xc = fminf(fmaxf(x, 0.0f), 1.0f);
  int k = j + 3;
  float left[4], right[4];
  N[0] = 1.0f;
#pragma unroll
  for (int jj = 1; jj <= 3; ++jj) {
    left[jj] = xc - knotv(k + 1 - jj);
    right[jj] = knotv(k + jj) - xc;
    float saved = 0.0f;
#pragma unroll
    for (int r = 0; r < jj; ++r) {
      float temp = N[r] * rcpf(right[r + 1] + left[jj - r]);
      N[r] = saved + right[r + 1] * temp;
      saved = left[jj - r] * temp;
    }
    N[jj] = saved;
  }
}

__device__ __forceinline__ void eval_point(float x, float y, float z, int jx,
                                           int jy, int jz,
                                           const float* __restrict__ cp,
                                           float o[3]) {
  float Nx[4], Ny[4], Nz[4];
  basis4(x, jx, Nx);
  basis4(y, jy, Ny);
  basis4(z, jz, Nz);
  float ax = 0, ay = 0, az = 0;
#pragma unroll 1
  for (int c = 0; c < 4; ++c) {
#pragma unroll
    for (int b = 0; b < 4; ++b) {
      float w = Ny[b] * Nz[c];
      const float* row = cp + 3 * (size_t)(jx + NC * (jy + b + NC * (jz + c)));
      vfloat4 f0, f1, f2;
      __builtin_memcpy(&f0, row + 0, 16);
      __builtin_memcpy(&f1, row + 4, 16);
      __builtin_memcpy(&f2, row + 8, 16);
      ax += w * (Nx[0] * f0.x + Nx[1] * f0.w + Nx[2] * f1.z + Nx[3] * f2.y);
      ay += w * (Nx[0] * f0.y + Nx[1] * f1.x + Nx[2] * f1.w + Nx[3] * f2.z);
      az += w * (Nx[0] * f0.z + Nx[1] * f1.y + Nx[2] * f2.x + Nx[3] * f2.w);
    }
  }
  o[0] = ax; o[1] = ay; o[2] = az;
}

// Exclusive prefix scan of arr[512] in LDS with 256 threads (2 elems/thread),
// shfl-based, 3 barriers. aux >= 4 ints. ALL 256 threads must call.
__device__ __forceinline__ void scan512_excl256(int* arr, int* aux) {
  int tid = threadIdx.x;
  int lane = tid & 63, wv = tid >> 6;  // 4 waves
  int a0 = arr[2 * tid], a1 = arr[2 * tid + 1];
  int s = a0 + a1;
  int inc = s;
#pragma unroll
  for (int off = 1; off < 64; off <<= 1) {
    int t = __shfl_up(inc, off, 64);
    if (lane >= off) inc += t;
  }
  if (lane == 63) aux[wv] = inc;
  __syncthreads();
  if (tid < 64) {
    int a = (tid < 4) ? aux[tid] : 0;
    int ainc = a;
#pragma unroll
    for (int off = 1; off < 4; off <<= 1) {
      int t = __shfl_up(ainc, off, 64);
      if (lane >= off) ainc += t;
    }
    if (tid < 4) aux[tid] = ainc - a;  // exclusive wave offsets
  }
  __syncthreads();
  int excl = (inc - s) + aux[wv];
  arr[2 * tid] = excl;
  arr[2 * tid + 1] = excl + a0;
  __syncthreads();
}

// ---------------- scatter: LDS-staged, cell-ordered coalesced writes --------
// CHUNK_S=2048, 489 blocks (R16-proven optimum; padded gcursor).

__global__ __launch_bounds__(256) void scatter_staged(
    const float* __restrict__ q, int* __restrict__ gcursor,
    int* __restrict__ ovfcnt, float4* __restrict__ ovf,
    float4* __restrict__ sorted, int nq) {
  __shared__ int hist[NCELLS];   // counts -> (after scan) local excl base
  __shared__ int gb[NCELLS];     // global segment base per cell
  __shared__ int lcur[NCELLS];   // local rank cursors
  __shared__ int aux[4];
  __shared__ float4 stage[CHUNK_S];  // 32 KB
  __shared__ int addr[CHUNK_S];      // 8 KB
  int tid = threadIdx.x;
  int s = blockIdx.x * CHUNK_S, e = min(nq, s + CHUNK_S);
  int nblk = e - s;
  hist[tid] = 0; hist[tid + 256] = 0;
  lcur[tid] = 0; lcur[tid + 256] = 0;
  __syncthreads();

  float xs[8], ys[8], zs[8];
  int cells[8];
  unsigned us[8];
#pragma unroll
  for (int it = 0; it < 8; ++it) {
    int i = s + it * 256 + tid;
    cells[it] = -1;
    if (i < e) {
      float xyz[3];
      __builtin_memcpy(xyz, q + 3 * (size_t)i, 12);
      xs[it] = xyz[0]; ys[it] = xyz[1]; zs[it] = xyz[2];
      int jx = span_of(xyz[0]), jy = span_of(xyz[1]), jz = span_of(xyz[2]);
      cells[it] = (jx >> 3) + 8 * (jy >> 3) + 64 * (jz >> 3);
      us[it] = (unsigned)i | ((unsigned)(jx & 7) << 20) |
               ((unsigned)(jy & 7) << 23) | ((unsigned)(jz & 7) << 26);
      atomicAdd(&hist[cells[it]], 1);
    }
  }
  __syncthreads();
  // claim global segment per nonempty cell; padded counters: 1 per 128B line
  int n0 = hist[tid], n1 = hist[tid + 256];
  gb[tid] = n0 ? atomicAdd(&gcursor[tid * GSTRIDE], n0) : 0;
  gb[tid + 256] = n1 ? atomicAdd(&gcursor[(tid + 256) * GSTRIDE], n1) : 0;
  scan512_excl256(hist, aux);  // hist[c] = local excl base (internal barriers)
  // stage in cell-sorted order
#pragma unroll
  for (int it = 0; it < 8; ++it) {
    int cell = cells[it];
    if (cell < 0) continue;
    int rank = atomicAdd(&lcur[cell], 1);
    int rloc = hist[cell] + rank;
    int rg = gb[cell] + rank;
    if (rg < CAP) {
      stage[rloc] = make_float4(xs[it], ys[it], zs[it],
                                __int_as_float((int)us[it]));
      addr[rloc] = cell * CAP + rg;
    } else {
      addr[rloc] = -1;
      int p = atomicAdd(ovfcnt, 1);
      if (p < OVF_CAP)
        ovf[p] = make_float4(xs[it], ys[it], zs[it],
                             __int_as_float((int)(us[it] & 0xFFFFFu)));
    }
  }
  __syncthreads();
  // drain: consecutive lanes -> consecutive addresses within cell segments
  for (int j = tid; j < nblk; j += 256) {
    int a = addr[j];
    if (a >= 0) sorted[a] = stage[j];
  }
}

// ---------------- eval: third-cell blocks, LDS window + subspan sort --------
// 256 thr = 1 wave/SIMD; 1536 blocks, LDS 25.6KB -> 6 blocks/CU, all
// resident. XCD swizzle keeps a cell's 3 parts on one XCD's L2.
// R17: window stage via single 16B load/element (was 3 scalar loads);
// .w lane is garbage and never read by the math; end-of-buffer guarded.

__global__ __launch_bounds__(256) void eval_kernel(
    const float4* __restrict__ sorted, const int* __restrict__ cellcnt,
    const float* __restrict__ cp, float* __restrict__ out,
    const int* __restrict__ ovfcnt, const float4* __restrict__ ovf) {
  __shared__ float4 lds[WDIM * WDIM * WDIM];  // 21296 B
  __shared__ int bins[NCELLS];                // 2048 B
  __shared__ unsigned short order[PARTMAX];   // 1792 B
  __shared__ int aux[4];
  int tid = threadIdx.x;
  int lb = (int)((blockIdx.x & 7) * (EVAL_BLOCKS / 8) + (blockIdx.x >> 3));
  int cid = lb / NPART, part = lb % NPART;
  int cnt = min(cellcnt[cid * GSTRIDE], CAP);
  int h = cnt / NPART;
  int q0 = part * h;
  int n = (part == NPART - 1) ? (cnt - 2 * h) : h;

  if (n > 0) {  // block-uniform; barriers inside are safe
    size_t base = (size_t)cid * CAP + q0;
    int ox = (cid & 7) * 8, oy = ((cid >> 3) & 7) * 8, oz = (cid >> 6) * 8;

    // stage 11^3 control-point window (L2/L3-resident source), 16B loads
    for (int e2 = tid; e2 < WDIM * WDIM * WDIM; e2 += 256) {
      int lx = e2 % WDIM, t = e2 / WDIM;
      int ly = t % WDIM, lz = t / WDIM;
      int gx = min(ox + lx, NC - 1), gy = min(oy + ly, NC - 1),
          gz = min(oz + lz, NC - 1);
      int gidx = gx + NC * (gy + NC * gz);
      const float* p = cp + 3 * (size_t)gidx;
      float4 v;
      if (gidx < NC * NC * NC - 1) {
        __builtin_memcpy(&v, p, 16);  // xyz + next.x (w unused by math)
      } else {
        v = make_float4(p[0], p[1], p[2], 0.0f);  // last element: no overrun
      }
      lds[e2] = v;
    }
    bins[tid] = 0;
    bins[tid + 256] = 0;
    // key probe: only the .w word (subspan key = lx + 8*ly + 64*lz)
    int k[4], r[4];
#pragma unroll
    for (int pr = 0; pr < 4; ++pr) {
      k[pr] = -1;
      r[pr] = 0;
      if (tid + pr * 256 < n)
        k[pr] = (int)(((unsigned)__float_as_int(
                          ((const float*)(sorted + base + tid + pr * 256))[3])
                       >> 20) & 511u);
    }
    __syncthreads();
#pragma unroll
    for (int pr = 0; pr < 4; ++pr)
      if (k[pr] >= 0) r[pr] = atomicAdd(&bins[k[pr]], 1);
    __syncthreads();
    scan512_excl256(bins, aux);
#pragma unroll
    for (int pr = 0; pr < 4; ++pr)
      if (k[pr] >= 0)
        order[bins[k[pr]] + r[pr]] = (unsigned short)(tid + pr * 256);
    __syncthreads();

    for (int t2 = tid; t2 < n; t2 += 256) {
      int lidx = order[t2];
      float4 sp = sorted[base + lidx];  // L1/L2-resident (just probed)
      unsigned u = (unsigned)__float_as_int(sp.w);
      int oi = (int)(u & 0xFFFFFu);
      int lx0 = (int)((u >> 20) & 7), ly0 = (int)((u >> 23) & 7),
          lz0 = (int)((u >> 26) & 7);
      float Nx[4], Ny[4], Nz[4];
      basis4(sp.x, ox + lx0, Nx);
      basis4(sp.y, oy + ly0, Ny);
      basis4(sp.z, oz + lz0, Nz);

      float ax = 0.0f, ay = 0.0f, az = 0.0f;
#pragma unroll
      for (int c = 0; c < 4; ++c) {
#pragma unroll
        for (int b = 0; b < 4; ++b) {
          float w = Ny[b] * Nz[c];
          const float4* row = &lds[((lz0 + c) * WDIM + (ly0 + b)) * WDIM + lx0];
          float4 p0 = row[0], p1 = row[1], p2 = row[2], p3 = row[3];
          ax += w * (Nx[0] * p0.x + Nx[1] * p1.x + Nx[2] * p2.x + Nx[3] * p3.x);
          ay += w * (Nx[0] * p0.y + Nx[1] * p1.y + Nx[2] * p2.y + Nx[3] * p3.y);
          az += w * (Nx[0] * p0.z + Nx[1] * p1.z + Nx[2] * p2.z + Nx[3] * p3.z);
        }
      }
      float o[3] = {ax, ay, az};
      __builtin_memcpy(out + 3 * (size_t)oi, o, 12);
    }
  }

  // fused overflow tail (ovf list complete: scatter finished before launch)
  int novf = min(*ovfcnt, OVF_CAP);
  for (int i = blockIdx.x * 256 + tid; i < novf; i += EVAL_BLOCKS * 256) {
    float4 sp = ovf[i];
    int oi = __float_as_int(sp.w);
    float o[3];
    eval_point(sp.x, sp.y, sp.z, span_of(sp.x), span_of(sp.y), span_of(sp.z),
               cp, o);
    __builtin_memcpy(out + 3 * (size_t)oi, o, 12);
  }
}

// ---------------- fallback: direct ----------------
__global__ __launch_bounds__(256) void spline_direct_kernel(
    const float* __restrict__ q, const float* __restrict__ cp,
    float* __restrict__ out, int nq) {
  int i = blockIdx.x * 256 + threadIdx.x;
  if (i >= nq) return;
  float xyz[3];
  __builtin_memcpy(xyz, q + 3 * (size_t)i, 12);
  float o[3];
  eval_point(xyz[0], xyz[1], xyz[2], span_of(xyz[0]), span_of(xyz[1]),
             span_of(xyz[2]), cp, o);
  __builtin_memcpy(out + 3 * (size_t)i, o, 12);
}

extern "C" void kernel_launch(void* const* d_in, const int* in_sizes, int n_in,
                              void* d_out, int out_size, void* d_ws,
                              size_t ws_size, hipStream_t stream) {
  const float* queries = (const float*)d_in[0];
  const float* control = (const float*)d_in[1];
  float* out = (float*)d_out;
  int nq = in_sizes[0] / 3;

  // ws: gcursor[512*GSTRIDE] | ovfcnt | pad16 | ovf[OVF_CAP] f4 | sorted f4
  size_t meta = ((size_t)NCELLS * GSTRIDE + 1) * sizeof(int);
  size_t metap = (meta + 15) & ~15ull;
  size_t need = metap + (size_t)OVF_CAP * 16 + (size_t)NCELLS * CAP * 16;

  if (nq <= (1 << 20) && ws_size >= need) {
    int* gcursor = (int*)d_ws;
    int* ovfcnt = gcursor + (size_t)NCELLS * GSTRIDE;
    float4* ovf = (float4*)((char*)d_ws + metap);
    float4* sorted = ovf + OVF_CAP;
    hipMemsetAsync(d_ws, 0, meta, stream);
    int nb = (nq + CHUNK_S - 1) / CHUNK_S;
    scatter_staged<<<nb, 256, 0, stream>>>(queries, gcursor, ovfcnt, ovf,
                                           sorted, nq);
    eval_kernel<<<EVAL_BLOCKS, 256, 0, stream>>>(sorted, gcursor, control, out,
                                                 ovfcnt, ovf);
  } else {
    spline_direct_kernel<<<(nq + 255) / 256, 256, 0, stream>>>(queries, control,
                                                               out, nq);
  }
}